// Round 1
// baseline (354.088 us; speedup 1.0000x reference)
//
#include <hip/hip_runtime.h>

// Histcounts: per-row fixed-width histogram.
// B=4096 rows, N=16384 fp32 values/row in [0,256), NBINS=100 over [0,256].
// bin = clamp(floor(100 * trunc(x) / 256), 0, 99)  -- exact in int math:
//   (25*xi)>>6  with xi clamped to [0,256].
//
// Strategy: 1 block / row, 256 threads, float4 loads (64 values/thread),
// 4 per-wave private LDS histograms to kill cross-wave same-address atomic
// serialization, then a 4-way reduce + coalesced fp32 store.

#define NBINS 100
#define NCOL  16384
#define BLOCK 256

__global__ __launch_bounds__(BLOCK) void histcounts_kernel(
    const float* __restrict__ x, float* __restrict__ out) {

    __shared__ unsigned int hist[4 * NBINS];

    const int row  = blockIdx.x;
    const int tid  = threadIdx.x;
    const int wave = tid >> 6;          // 0..3

    // zero the 4 private histograms
    for (int i = tid; i < 4 * NBINS; i += BLOCK) hist[i] = 0u;
    __syncthreads();

    const float4* rowp = (const float4*)(x + (size_t)row * NCOL);
    unsigned int* myhist = &hist[wave * NBINS];

    // 16384 floats / 4 per float4 / 256 threads = 16 iterations
    #pragma unroll 4
    for (int i = 0; i < NCOL / 4 / BLOCK; ++i) {
        float4 v = rowp[tid + i * BLOCK];

        int x0 = (int)v.x;  // trunc toward zero; inputs are >= 0
        int x1 = (int)v.y;
        int x2 = (int)v.z;
        int x3 = (int)v.w;

        // clip into [0, 256] per tf.histogram_fixed_width semantics
        x0 = min(max(x0, 0), 256);
        x1 = min(max(x1, 0), 256);
        x2 = min(max(x2, 0), 256);
        x3 = min(max(x3, 0), 256);

        int b0 = min((25 * x0) >> 6, NBINS - 1);
        int b1 = min((25 * x1) >> 6, NBINS - 1);
        int b2 = min((25 * x2) >> 6, NBINS - 1);
        int b3 = min((25 * x3) >> 6, NBINS - 1);

        atomicAdd(&myhist[b0], 1u);
        atomicAdd(&myhist[b1], 1u);
        atomicAdd(&myhist[b2], 1u);
        atomicAdd(&myhist[b3], 1u);
    }
    __syncthreads();

    // reduce 4 private histograms and store (threads 0..99 active)
    for (int b = tid; b < NBINS; b += BLOCK) {
        unsigned int s = hist[b] + hist[NBINS + b] +
                         hist[2 * NBINS + b] + hist[3 * NBINS + b];
        out[(size_t)row * NBINS + b] = (float)s;
    }
}

extern "C" void kernel_launch(void* const* d_in, const int* in_sizes, int n_in,
                              void* d_out, int out_size, void* d_ws, size_t ws_size,
                              hipStream_t stream) {
    const float* x = (const float*)d_in[0];
    float* out = (float*)d_out;

    const int B = 4096;  // rows; in_sizes[0] == B * NCOL
    histcounts_kernel<<<B, BLOCK, 0, stream>>>(x, out);
}

// Round 2
// 354.063 us; speedup vs baseline: 1.0001x; 1.0001x over previous
//
#include <hip/hip_runtime.h>

// Histcounts: per-row fixed-width histogram.
// B=4096 rows, N=16384 fp32 values/row in [0,256), NBINS=100 over [0,256].
// bin = clamp((25 * clamp((int)x, 0, 256)) >> 6, 0, 99)  -- exact int math.
//
// Round 2: bank/lane-private LDS histogram columns.
//   hist[bin*64 + lane]  (bin-major, 64 columns)
// Lane i always hits bank i%32 -> zero same-address collisions within a
// wave-instruction, only the free 2-way bank alias (i, i+32). Cross-wave
// column sharing (4 waves/block) is pipelined atomic bank traffic (~1/cy/bank).
// Round 1 (4 wave-private copies, scattered) cost ~85 cy per ds_atomic
// wave-op from same-address serialization -> 354 us. This layout should cut
// that to ~5 cy, putting us near the 43 us HBM floor.

#define NBINS 100
#define NCOL  16384
#define BLOCK 256
#define NCOPY 64   // one column per lane of a wave

__global__ __launch_bounds__(BLOCK) void histcounts_kernel(
    const float* __restrict__ x, float* __restrict__ out) {

    __shared__ unsigned int hist[NBINS * NCOPY];   // 25.6 KB

    const int row  = blockIdx.x;
    const int tid  = threadIdx.x;
    const int lane = tid & 63;

    // zero the histogram columns
    for (int i = tid; i < NBINS * NCOPY; i += BLOCK) hist[i] = 0u;
    __syncthreads();

    const float4* rowp = (const float4*)(x + (size_t)row * NCOL);

    // 16384 floats / 4 per float4 / 256 threads = 16 iterations
    #pragma unroll 4
    for (int i = 0; i < NCOL / 4 / BLOCK; ++i) {
        float4 v = rowp[tid + i * BLOCK];

        int x0 = (int)v.x;  // trunc toward zero; inputs >= 0
        int x1 = (int)v.y;
        int x2 = (int)v.z;
        int x3 = (int)v.w;

        x0 = min(max(x0, 0), 256);
        x1 = min(max(x1, 0), 256);
        x2 = min(max(x2, 0), 256);
        x3 = min(max(x3, 0), 256);

        int b0 = min((25 * x0) >> 6, NBINS - 1);
        int b1 = min((25 * x1) >> 6, NBINS - 1);
        int b2 = min((25 * x2) >> 6, NBINS - 1);
        int b3 = min((25 * x3) >> 6, NBINS - 1);

        // lane-private columns: no intra-wave same-address collisions
        atomicAdd(&hist[b0 * NCOPY + lane], 1u);
        atomicAdd(&hist[b1 * NCOPY + lane], 1u);
        atomicAdd(&hist[b2 * NCOPY + lane], 1u);
        atomicAdd(&hist[b3 * NCOPY + lane], 1u);
    }
    __syncthreads();

    // reduce 64 columns per bin; rotate start index so lane b sweeps banks
    // (bank of hist[b*64 + j] is j%32 -> rotation spreads lanes uniformly)
    if (tid < NBINS) {
        unsigned int s = 0;
        const int base = tid * NCOPY;
        #pragma unroll
        for (int k = 0; k < NCOPY; ++k)
            s += hist[base + ((k + tid) & (NCOPY - 1))];
        out[(size_t)row * NBINS + tid] = (float)s;
    }
}

extern "C" void kernel_launch(void* const* d_in, const int* in_sizes, int n_in,
                              void* d_out, int out_size, void* d_ws, size_t ws_size,
                              hipStream_t stream) {
    const float* x = (const float*)d_in[0];
    float* out = (float*)d_out;

    const int B = 4096;  // rows; in_sizes[0] == B * NCOL
    histcounts_kernel<<<B, BLOCK, 0, stream>>>(x, out);
}

// Round 3
// 353.278 us; speedup vs baseline: 1.0023x; 1.0022x over previous
//
#include <hip/hip_runtime.h>

// Histcounts: per-row fixed-width histogram.
// B=4096 rows, N=16384 fp32/row in [0,256), NBINS=100 over [0,256].
// bin = clamp((25 * clamp((int)x, 0, 256)) >> 6, 0, 99)  -- exact int math.
//
// Round 3: MLP boost. Rounds 1+2 (different LDS layouts) timed within 25 ns
// of each other => kernel is HBM-streaming-bound (~40 us slice of the 354 us
// bench figure; the rest is fixed harness poison fills). Only remaining
// lever: more loads in flight. Batch 8 global float4 loads per thread before
// any bin processing (vs unroll-4 with interleaved dependent atomics).
// LDS: bank/lane-private columns hist[bin*64+lane] -- atomic cost fully
// hidden under the HBM stream (proven by round1==round2).

#define NBINS 100
#define NCOL  16384
#define BLOCK 256
#define NCOPY 64                       // one column per lane
#define ITERS (NCOL / 4 / BLOCK)       // 16 float4 per thread
#define BATCH 8

__global__ __launch_bounds__(BLOCK) void histcounts_kernel(
    const float* __restrict__ x, float* __restrict__ out) {

    __shared__ unsigned int hist[NBINS * NCOPY];   // 25.6 KB

    const int row  = blockIdx.x;
    const int tid  = threadIdx.x;
    const int lane = tid & 63;

    for (int i = tid; i < NBINS * NCOPY; i += BLOCK) hist[i] = 0u;
    __syncthreads();

    const float4* rowp = (const float4*)(x + (size_t)row * NCOL);

    float4 v[BATCH];
    #pragma unroll
    for (int half = 0; half < ITERS / BATCH; ++half) {
        // issue 8 independent 16B loads back-to-back (2 KB in flight/thread-batch)
        #pragma unroll
        for (int j = 0; j < BATCH; ++j)
            v[j] = rowp[tid + (half * BATCH + j) * BLOCK];

        #pragma unroll
        for (int j = 0; j < BATCH; ++j) {
            int x0 = (int)v[j].x;   // trunc toward zero
            int x1 = (int)v[j].y;
            int x2 = (int)v[j].z;
            int x3 = (int)v[j].w;

            x0 = min(max(x0, 0), 256);
            x1 = min(max(x1, 0), 256);
            x2 = min(max(x2, 0), 256);
            x3 = min(max(x3, 0), 256);

            int b0 = min((25 * x0) >> 6, NBINS - 1);
            int b1 = min((25 * x1) >> 6, NBINS - 1);
            int b2 = min((25 * x2) >> 6, NBINS - 1);
            int b3 = min((25 * x3) >> 6, NBINS - 1);

            // lane-private columns: no intra-wave same-address collisions
            atomicAdd(&hist[b0 * NCOPY + lane], 1u);
            atomicAdd(&hist[b1 * NCOPY + lane], 1u);
            atomicAdd(&hist[b2 * NCOPY + lane], 1u);
            atomicAdd(&hist[b3 * NCOPY + lane], 1u);
        }
    }
    __syncthreads();

    // reduce 64 columns per bin; rotated sweep spreads lanes over banks
    if (tid < NBINS) {
        unsigned int s = 0;
        const int base = tid * NCOPY;
        #pragma unroll
        for (int k = 0; k < NCOPY; ++k)
            s += hist[base + ((k + tid) & (NCOPY - 1))];
        out[(size_t)row * NBINS + tid] = (float)s;
    }
}

extern "C" void kernel_launch(void* const* d_in, const int* in_sizes, int n_in,
                              void* d_out, int out_size, void* d_ws, size_t ws_size,
                              hipStream_t stream) {
    const float* x = (const float*)d_in[0];
    float* out = (float*)d_out;

    const int B = 4096;  // rows; in_sizes[0] == B * NCOL
    histcounts_kernel<<<B, BLOCK, 0, stream>>>(x, out);
}